// Round 5
// baseline (192.235 us; speedup 1.0000x reference)
//
#include <hip/hip_runtime.h>

// Adder2D: out[n,h,w,f] = bias[f] - sum_{ij,c} |x[..,c] - K[ij,c,f]|
// Identity: sum|x-w| = 2*sum max(x,w) - sum_x (precomputed Sx + 3x3 combine)
//                      - sum_w (folded into biasW).
// Inner loop: v_pk_max_f16 + v_pk_add_f16 per channel-pair (measured ~4.3cyc/VOP3P
// => ~132us issue floor). This round removes the ~29% VALU-idle:
//   - X staged as a 3-row halo ONCE per cs (3x3 reuse; was 9x restaged)
//   - W pre-packed f16 + pre-swizzled into d_ws by precompute kernel; main kernel
//     stages it with global_load_lds width=16 (zero VALU, zero VGPR)
//   - W double-buffered in LDS, next chunk's loads issued before compute (latency
//     hidden under ~1400cyc of MFMA-free VOP3P work); ONE barrier per chunk.

typedef _Float16 v2h  __attribute__((ext_vector_type(2)));
typedef __fp16   v2hb __attribute__((ext_vector_type(2)));
typedef float    v4f  __attribute__((ext_vector_type(4)));

#define CC 128
#define FF 128

// ws layout in 4B words: Sx[32768] | biasW[128] | Wpk[18*4096]
#define WS_SX    0
#define WS_BIASW 32768
#define WS_WPK   32896

static __device__ __forceinline__ unsigned pack2(float a, float b) {
    return __builtin_bit_cast(unsigned, __builtin_amdgcn_cvt_pkrtz(a, b));
}

// ---------------- precompute: Sx, biasW, packed+swizzled W ----------------
__global__ __launch_bounds__(256)
void precompute_kernel(const float* __restrict__ x,
                       const float* __restrict__ kern,
                       const float* __restrict__ bias,
                       float* __restrict__ ws)
{
    const int t = threadIdx.x;
    const int b = blockIdx.x;
    if (b < 512) {
        // Sx[px] = sum_c x[px,c]; 4 threads/pixel, coalesced v4f
        float* Sx = ws + WS_SX;
        const int px = (b << 6) + (t >> 2);
        const int q  = t & 3;
        const float* s = x + px * CC + (q << 5);
        float acc = 0.f;
#pragma unroll
        for (int k = 0; k < 8; ++k) {
            v4f v = *(const v4f*)(s + (k << 2));
            acc += v.x + v.y + v.z + v.w;
        }
        acc += __shfl_xor(acc, 1);
        acc += __shfl_xor(acc, 2);
        if (q == 0) Sx[px] = acc;
    } else if (b == 512) {
        // biasW[f] = bias[f] + sum over 1152 rows of kern[row][f]
        __shared__ v4f red4[256];
        float* biasW = ws + WS_BIASW;
        v4f acc = {0.f, 0.f, 0.f, 0.f};
        const int c4 = t & 31;
#pragma unroll 8
        for (int i = 0; i < 144; ++i) {
            const int row = (i << 3) + (t >> 5);
            acc += *(const v4f*)(kern + row * FF + (c4 << 2));
        }
        red4[t] = acc;
        __syncthreads();
        if (t < 128) {
            const int u = t >> 2, e = t & 3;
            float s = 0.f;
#pragma unroll
            for (int j = 0; j < 8; ++j) s += red4[u + (j << 5)][e];
            biasW[t] = bias[t] + s;
        }
    } else {
        // Wpk: chunk = cs*9+ij; within chunk: word[kk2*128 + (u^(u>>3))*4 + e]
        //      = pack2(K[ij*128+cs*64+2kk2][u*4+e], K[...+1][u*4+e])
        unsigned* Wpk = (unsigned*)ws + WS_WPK;
        const int wb    = b - 513;             // 0..287
        const int chunk = wb >> 4;             // 0..17
        const int idx   = ((wb & 15) << 8) + t; // 0..4095
        const int kk2   = idx >> 7;
        const int rest  = idx & 127;
        const int u     = rest >> 2;
        const int e     = rest & 3;
        const int cs    = chunk / 9;
        const int ij    = chunk - cs * 9;
        const int ch0   = ij * CC + (cs << 6) + (kk2 << 1);
        const float w0  = kern[ch0 * FF + (u << 2) + e];
        const float w1  = kern[(ch0 + 1) * FF + (u << 2) + e];
        Wpk[(chunk << 12) + (kk2 << 7) + ((u ^ (u >> 3)) << 2) + e] = pack2(w0, w1);
    }
}

// -------------------------------- main kernel --------------------------------
__global__ __launch_bounds__(256, 3)
void adder2d_kernel(const float* __restrict__ x,
                    const unsigned* __restrict__ Wpk,
                    const float* __restrict__ biasW,
                    const float* __restrict__ Sx,
                    float* __restrict__ out)
{
    __shared__ unsigned Xs[32 * 102];   // 13.1 KB: [kk2][row 0..2][col 0..33] f16-pairs
    __shared__ unsigned Wb0[4096];      // 16 KB double-buffered W chunk
    __shared__ unsigned Wb1[4096];
    __shared__ float    s3arr[34];

    const int t = threadIdx.x;
    const int r = blockIdx.x;           // 0..1023 global row
    const int n = r >> 5;
    const int h = r & 31;

    const int pg = t >> 4;
    const int fg = t & 15;
    const int f0 = fg << 3;
    const int p0 = pg << 1;
    const int u1 = fg << 1, u2 = u1 | 1;
    const int wu1 = (u1 ^ (u1 >> 3)) << 2;   // swizzled W read offsets (words)
    const int wu2 = (u2 ^ (u2 >> 3)) << 2;

    // 3-row column sums of Sx (SAME pad: row-OOB -> 0); s3arr[j] = col j-1, halos 0
    if (t < 32) {
        float s3 = 0.f;
#pragma unroll
        for (int di = -1; di <= 1; ++di) {
            const int hh = h + di;
            if (0 <= hh && hh < 32) s3 += Sx[(n * 32 + hh) * 32 + t];
        }
        s3arr[t + 1] = s3;
    }
    if (t == 0) { s3arr[0] = 0.f; s3arr[33] = 0.f; }

    float accf[2][8];
#pragma unroll
    for (int pi = 0; pi < 2; ++pi)
#pragma unroll
        for (int fi = 0; fi < 8; ++fi) accf[pi][fi] = 0.f;

    const int sp = t >> 3;      // image px 0..31 -> X3 col sp+1
    const int sa = t & 7;       // channel octet

    const unsigned* wSrc = Wpk; // walks the 18 chunks sequentially

    for (int cs = 0; cs < 2; ++cs) {
        // ---- stage X3: 3 rows x 34 cols x 32 kk2 (halo cols/rows = 0) ----
        if (t < 192) {          // zero the 2 halo columns (wx = -1, 32)
            const int row  = t >> 6;
            const int rest = t & 63;
            Xs[(rest >> 1) * 102 + row * 34 + (rest & 1) * 33] = 0u;
        }
#pragma unroll
        for (int row = 0; row < 3; ++row) {
            const int hh = h + row - 1;
            v4f g0 = {0.f,0.f,0.f,0.f}, g1 = {0.f,0.f,0.f,0.f};
            if (0 <= hh && hh < 32) {
                const float* s = x + (((n * 32 + hh) * 32 + sp) * CC) + (cs << 6) + (sa << 3);
                g0 = *(const v4f*)s;
                g1 = *(const v4f*)(s + 4);
            }
            const int kb = sa << 2;
            const int base = row * 34 + sp + 1;
            Xs[(kb + 0) * 102 + base] = pack2(g0.x, g0.y);
            Xs[(kb + 1) * 102 + base] = pack2(g0.z, g0.w);
            Xs[(kb + 2) * 102 + base] = pack2(g1.x, g1.y);
            Xs[(kb + 3) * 102 + base] = pack2(g1.z, g1.w);
        }
        // ---- stage W chunk (cs,ij=0) into Wb0 via direct-to-LDS DMA ----
#pragma unroll
        for (int p = 0; p < 4; ++p) {
            __builtin_amdgcn_global_load_lds(
                (const __attribute__((address_space(1))) unsigned*)(wSrc + (p << 10) + t * 4),
                (__attribute__((address_space(3))) unsigned*)&Wb0[(p << 10) + ((t >> 6) << 8)],
                16, 0, 0);
        }
        __syncthreads();   // drains gl_lds (vmcnt0) + X3 writes

        unsigned* wCur = Wb0;
        unsigned* wNxt = Wb1;

        for (int ij = 0; ij < 9; ++ij) {
            // prefetch next W chunk into the other buffer (latency hides under compute)
            if (ij < 8) {
#pragma unroll
                for (int p = 0; p < 4; ++p) {
                    __builtin_amdgcn_global_load_lds(
                        (const __attribute__((address_space(1))) unsigned*)(wSrc + 4096 + (p << 10) + t * 4),
                        (__attribute__((address_space(3))) unsigned*)&wNxt[(p << 10) + ((t >> 6) << 8)],
                        16, 0, 0);
                }
            }
            const int di = ij / 3;
            const int dj = ij - di * 3;
            const int xbase = di * 34 + p0 + dj;

            unsigned acc2[2][8];
#pragma unroll
            for (int pi = 0; pi < 2; ++pi)
#pragma unroll
                for (int fi = 0; fi < 8; ++fi) acc2[pi][fi] = 0u;

#pragma unroll 8
            for (int kk2 = 0; kk2 < 32; ++kk2) {
                const unsigned x0 = Xs[kk2 * 102 + xbase];
                const unsigned x1 = Xs[kk2 * 102 + xbase + 1];
                const uint4 wa = *(const uint4*)&wCur[(kk2 << 7) + wu1];
                const uint4 wb = *(const uint4*)&wCur[(kk2 << 7) + wu2];
                const unsigned w8[8] = {wa.x, wa.y, wa.z, wa.w, wb.x, wb.y, wb.z, wb.w};
#pragma unroll
                for (int pi = 0; pi < 2; ++pi) {
                    const unsigned xp = (pi == 0) ? x0 : x1;
#pragma unroll
                    for (int fi = 0; fi < 8; ++fi) {
                        unsigned m;
                        asm("v_pk_max_f16 %0, %1, %2" : "=v"(m) : "v"(xp), "v"(w8[fi]));
                        asm("v_pk_add_f16 %0, %1, %0" : "+v"(acc2[pi][fi]) : "v"(m));
                    }
                }
            }

            // dump f16 pair-partials (<=64 terms) into f32
#pragma unroll
            for (int pi = 0; pi < 2; ++pi)
#pragma unroll
                for (int fi = 0; fi < 8; ++fi) {
#if __has_builtin(__builtin_amdgcn_fdot2)
                    const v2hb av = __builtin_bit_cast(v2hb, acc2[pi][fi]);
                    const v2hb ones = {(__fp16)1.0f, (__fp16)1.0f};
                    accf[pi][fi] = __builtin_amdgcn_fdot2(av, ones, accf[pi][fi], false);
#else
                    const v2h ah = __builtin_bit_cast(v2h, acc2[pi][fi]);
                    accf[pi][fi] += (float)ah.x + (float)ah.y;
#endif
                }

            __syncthreads();        // next chunk landed; wCur free for reuse
            wSrc += 4096;
            unsigned* tmp = wCur; wCur = wNxt; wNxt = tmp;
        }
    }

    // ---- epilogue: out = biasW + S9 - 2*sum(max) ----
    const v4f b0 = *(const v4f*)(biasW + f0);
    const v4f b1 = *(const v4f*)(biasW + f0 + 4);
#pragma unroll
    for (int pi = 0; pi < 2; ++pi) {
        const int p = p0 + pi;
        const float s9 = s3arr[p] + s3arr[p + 1] + s3arr[p + 2];
        float* dst = out + ((r * 32 + p) * FF) + f0;
        v4f o0, o1;
        o0.x = fmaf(-2.f, accf[pi][0], b0.x + s9);
        o0.y = fmaf(-2.f, accf[pi][1], b0.y + s9);
        o0.z = fmaf(-2.f, accf[pi][2], b0.z + s9);
        o0.w = fmaf(-2.f, accf[pi][3], b0.w + s9);
        o1.x = fmaf(-2.f, accf[pi][4], b1.x + s9);
        o1.y = fmaf(-2.f, accf[pi][5], b1.y + s9);
        o1.z = fmaf(-2.f, accf[pi][6], b1.z + s9);
        o1.w = fmaf(-2.f, accf[pi][7], b1.w + s9);
        *(v4f*)dst = o0;
        *(v4f*)(dst + 4) = o1;
    }
}

extern "C" void kernel_launch(void* const* d_in, const int* in_sizes, int n_in,
                              void* d_out, int out_size, void* d_ws, size_t ws_size,
                              hipStream_t stream) {
    const float* x    = (const float*)d_in[0];
    const float* kern = (const float*)d_in[1];
    const float* bias = (const float*)d_in[2];
    float* out = (float*)d_out;
    float* ws  = (float*)d_ws;   // needs (32768+128+73728)*4 = 426,496 B

    precompute_kernel<<<801, 256, 0, stream>>>(x, kern, bias, ws);
    adder2d_kernel<<<1024, 256, 0, stream>>>(x,
                                             (const unsigned*)ws + WS_WPK,
                                             ws + WS_BIASW,
                                             ws + WS_SX,
                                             out);
}